// Round 2
// baseline (3551.839 us; speedup 1.0000x reference)
//
#include <hip/hip_runtime.h>
#include <hip/hip_bf16.h>

typedef unsigned short ushort;
typedef __attribute__((ext_vector_type(8))) short short8;   // 8 bf16 (4 VGPRs) MFMA operand
typedef __attribute__((ext_vector_type(4))) float floatx4;  // MFMA accumulator

#define TB   1024   // T
#define BB   4      // B
#define HH   1024   // H
#define KK   512    // K (gate dim)
#define VD   1024   // Vd
#define OO   1024   // O
#define NVOC 32000
#define NL   2
#define NTOK (BB*TB)
#define NHALF 16000  // W_head transposed+GEMMed in two column chunks (ws budget)

__device__ __forceinline__ float bf2f(ushort u) { return __uint_as_float(((unsigned)u) << 16); }
__device__ __forceinline__ ushort f2bf(float f) {
    unsigned x = __float_as_uint(f);
    return (ushort)((x + 0x7fffu + ((x >> 16) & 1u)) >> 16);   // RNE
}

// ---------------- dtype probe: fp32 data read as bf16 contains huge values ----------------
// flag=1 -> float32 inputs, flag=0 -> bf16 inputs.
__global__ void probe_k(const ushort* __restrict__ emb, int* __restrict__ flag) {
    __shared__ int any;
    if (threadIdx.x == 0) any = 0;
    __syncthreads();
    int bad = 0;
    for (int i = threadIdx.x; i < 32768; i += 256) {
        float a = fabsf(bf2f(emb[i]));
        if (a > 1e6f) bad = 1;          // impossible for genuine 0.02-scale bf16 data
    }
    if (bad) any = 1;                    // benign race: all writers store 1
    __syncthreads();
    if (threadIdx.x == 0) *flag = any;
}

// ---------------- bias normalize to bf16 ----------------
__global__ void cvt_bias_k(const void* __restrict__ src, ushort* __restrict__ dst, int n,
                           const int* __restrict__ flagp) {
    int i = blockIdx.x * 256 + threadIdx.x;
    if (i >= n) return;
    if (*flagp) dst[i] = f2bf(((const float*)src)[i]);
    else        dst[i] = ((const ushort*)src)[i];
}

// ---------------- transpose: in (R,C) row-major (+element offset) -> out (C,R) bf16 ----------------
__global__ __launch_bounds__(256) void transpose_k(const void* __restrict__ in_, size_t eoff,
                                                   ushort* __restrict__ out, int R, int C,
                                                   const int* __restrict__ flagp) {
    __shared__ ushort tile[32][33];
    const int bx = blockIdx.x * 32;     // col base (C dim)
    const int by = blockIdx.y * 32;     // row base (R dim)
    const int tx = threadIdx.x & 31;
    const int ty = threadIdx.x >> 5;    // 0..7
    if (*flagp) {
        const float* in = (const float*)in_ + eoff;
#pragma unroll
        for (int i = 0; i < 32; i += 8)
            tile[ty + i][tx] = f2bf(in[(size_t)(by + ty + i) * C + bx + tx]);
    } else {
        const ushort* in = (const ushort*)in_ + eoff;
#pragma unroll
        for (int i = 0; i < 32; i += 8)
            tile[ty + i][tx] = in[(size_t)(by + ty + i) * C + bx + tx];
    }
    __syncthreads();
#pragma unroll
    for (int i = 0; i < 32; i += 8)
        out[(size_t)(bx + ty + i) * R + by + tx] = tile[tx][ty + i];
}

// ---------------- embedding gather: h[t,:] = bf16(emb[ids[t],:]) ----------------
__global__ __launch_bounds__(256) void gather_k(const int* __restrict__ ids,
                                                const void* __restrict__ emb_,
                                                ushort* __restrict__ h,
                                                const int* __restrict__ flagp) {
    int t = blockIdx.x;
    int id = ids[t];
    int c = threadIdx.x * 4;  // 4 elems/thread * 256 = 1024
    if (*flagp) {
        const float* emb = (const float*)emb_;
        float4 v = *(const float4*)&emb[(size_t)id * HH + c];
        ushort4 o; o.x = f2bf(v.x); o.y = f2bf(v.y); o.z = f2bf(v.z); o.w = f2bf(v.w);
        *(ushort4*)&h[(size_t)t * HH + c] = o;
    } else {
        const ushort* emb = (const ushort*)emb_;
        *(uint2*)&h[(size_t)t * HH + c] = *(const uint2*)&emb[(size_t)id * HH + c];
    }
}

// ---------------- bf16 GEMM, B pre-transposed: C[M,N] = A[M,K] @ Bt[N,K]^T + bias ----------------
// MODE 0: bf16 out, single bias. MODE 1: fp32 out, fused qkgv epilogue (q | sig(k) | sig(g) | v).
// MODE 2: head — single bias, out dtype switched on *flagp (fp32 vs bf16).
// Tile 128x128x32, 256 threads = 4 waves (2x2 of 64x64), v_mfma_f32_16x16x32_bf16.
template<int MODE>
__global__ __launch_bounds__(256) void gemm_bt(
    const ushort* __restrict__ A, const ushort* __restrict__ Bt, void* __restrict__ Cv,
    const ushort* __restrict__ b0, const ushort* __restrict__ b1,
    const ushort* __restrict__ b2, const ushort* __restrict__ b3,
    int K, int ldc, int coloff, const int* __restrict__ flagp)
{
    // +8 pad -> row stride 80B = 20 banks: frag reads land 2-way max (free, m136)
    __shared__ ushort As[128][40];
    __shared__ ushort Bs[128][40];

    const int tid  = threadIdx.x;
    const int bm   = blockIdx.y * 128;
    const int bn   = blockIdx.x * 128;
    const int wave = tid >> 6, lane = tid & 63;
    const int wm   = (wave >> 1) * 64, wn = (wave & 1) * 64;
    const int l15  = lane & 15, quad = lane >> 4;

    floatx4 acc[4][4];
#pragma unroll
    for (int i = 0; i < 4; i++)
#pragma unroll
        for (int j = 0; j < 4; j++) acc[i][j] = (floatx4){0.f, 0.f, 0.f, 0.f};

    // staging map: thread -> row r0 (0..127), two 16B chunks at c0, c0+8
    const int r0 = tid >> 1;
    const int c0 = (tid & 1) * 16;
    const ushort* Aptr = A + (size_t)(bm + r0) * K + c0;
    const ushort* Bptr = Bt + (size_t)(bn + r0) * K + c0;
    ushort* Asl = &As[r0][c0];
    ushort* Bsl = &Bs[r0][c0];

    for (int kt = 0; kt < K; kt += 32) {
        uint4 a0  = *(const uint4*)(Aptr + kt);
        uint4 a1  = *(const uint4*)(Aptr + kt + 8);
        uint4 bv0 = *(const uint4*)(Bptr + kt);
        uint4 bv1 = *(const uint4*)(Bptr + kt + 8);
        *(uint4*)Asl = a0;  *(uint4*)(Asl + 8) = a1;
        *(uint4*)Bsl = bv0; *(uint4*)(Bsl + 8) = bv1;
        __syncthreads();

        short8 af[4], bfr[4];
#pragma unroll
        for (int i = 0; i < 4; i++) af[i]  = *(const short8*)&As[wm + i * 16 + l15][quad * 8];
#pragma unroll
        for (int i = 0; i < 4; i++) bfr[i] = *(const short8*)&Bs[wn + i * 16 + l15][quad * 8];
#pragma unroll
        for (int i = 0; i < 4; i++)
#pragma unroll
            for (int j = 0; j < 4; j++)
                acc[i][j] = __builtin_amdgcn_mfma_f32_16x16x32_bf16(af[i], bfr[j], acc[i][j], 0, 0, 0);
        __syncthreads();
    }

    const int f = (MODE == 2) ? *flagp : 0;

    // epilogue: D lane map col=lane&15, row=quad*4+r (verified m89/m91)
#pragma unroll
    for (int i = 0; i < 4; i++) {
#pragma unroll
        for (int j = 0; j < 4; j++) {
            const int col = bn + wn + j * 16 + l15;   // local column
            float bias; bool sig = false;
            if (MODE == 1) {
                if      (col < KK)     { bias = bf2f(b0[col]); }
                else if (col < 2 * KK) { bias = bf2f(b1[col - KK]);     sig = true; }
                else if (col < 3 * KK) { bias = bf2f(b2[col - 2 * KK]); sig = true; }
                else                   { bias = bf2f(b3[col - 3 * KK]); }
            } else {
                bias = bf2f(b0[col]);
            }
#pragma unroll
            for (int r = 0; r < 4; r++) {
                const int row = bm + wm + i * 16 + quad * 4 + r;
                float v = acc[i][j][r] + bias;
                if (sig) v = 1.f / (1.f + __expf(-v));
                const size_t idx = (size_t)row * ldc + coloff + col;
                if (MODE == 1)      ((float*)Cv)[idx]  = v;
                else if (MODE == 0) ((ushort*)Cv)[idx] = f2bf(v);
                else { if (f) ((float*)Cv)[idx] = v; else ((ushort*)Cv)[idx] = f2bf(v); }
            }
        }
    }
}

// ---------------- sequential gated scan ----------------
// qkgv: (B*T, 2560) fp32 rows = [q(512) | k(512) | g(512) | v(1024)]
// out:  (B*T, 1024) bf16 = einsum('bkv,bk->bv', state_t, q_t), state = state*g + k (outer) v
// grid (VD/16, B), 256 thr. Thread (kg=tid>>4, vt=tid&15) owns k in [kg*32,kg*32+32), v = v0+vt.
// State: 32 fp32 regs/thread. q/k/g double-buffered in LDS with per-kgroup bank rotation.
__global__ __launch_bounds__(256) void scan_k(const float* __restrict__ qkgv,
                                              ushort* __restrict__ outp)
{
    const int b  = blockIdx.y;
    const int v0 = blockIdx.x * 16;
    const int tid = threadIdx.x;
    const int vt = tid & 15;
    const int kg = tid >> 4;            // 0..15
    const int lane = tid & 63;
    const int wave = tid >> 6;
    const int rot = (kg & 3) * 8;       // bank rotation within wave

    __shared__ float sq[2][512], sk[2][512], sg[2][512];
    __shared__ float sv[2][16];
    __shared__ float wpart[4][16];

    float s[32];
#pragma unroll
    for (int j = 0; j < 32; j++) s[j] = 0.f;

    const size_t rowbase = (size_t)b * TB * 2560;

    { // stage t=0 into buffer 0 (rotated placement: elem i -> slot (i&~31)|(((i&31)+8*((i>>5)&3))&31))
        const float* row = qkgv + rowbase;
#pragma unroll
        for (int ii = 0; ii < 2; ii++) {
            int i = tid + ii * 256;
            int slot = (i & ~31) | (((i & 31) + ((i >> 5) & 3) * 8) & 31);
            sq[0][slot] = row[i];
            sk[0][slot] = row[512 + i];
            sg[0][slot] = row[1024 + i];
        }
        if (tid < 16) sv[0][tid] = row[1536 + v0 + tid];
    }
    __syncthreads();

    for (int t = 0; t < TB; t++) {
        const int cur = t & 1, nxt = cur ^ 1;
        if (t + 1 < TB) {   // prefetch next step
            const float* row = qkgv + rowbase + (size_t)(t + 1) * 2560;
#pragma unroll
            for (int ii = 0; ii < 2; ii++) {
                int i = tid + ii * 256;
                int slot = (i & ~31) | (((i & 31) + ((i >> 5) & 3) * 8) & 31);
                sq[nxt][slot] = row[i];
                sk[nxt][slot] = row[512 + i];
                sg[nxt][slot] = row[1024 + i];
            }
            if (tid < 16) sv[nxt][tid] = row[1536 + v0 + tid];
        }

        const float vv = sv[cur][vt];
        float po = 0.f;
        const int kb = kg * 32;
#pragma unroll
        for (int m = 0; m < 8; m++) {
            const int off = (m * 4 + rot) & 31;   // 4-run never wraps (rot%8==0, off%4==0)
            float4 g4 = *(const float4*)&sg[cur][kb + off];
            float4 k4 = *(const float4*)&sk[cur][kb + off];
            float4 q4 = *(const float4*)&sq[cur][kb + off];
            s[m*4+0] = fmaf(s[m*4+0], g4.x, k4.x * vv); po = fmaf(q4.x, s[m*4+0], po);
            s[m*4+1] = fmaf(s[m*4+1], g4.y, k4.y * vv); po = fmaf(q4.y, s[m*4+1], po);
            s[m*4+2] = fmaf(s[m*4+2], g4.z, k4.z * vv); po = fmaf(q4.z, s[m*4+2], po);
            s[m*4+3] = fmaf(s[m*4+3], g4.w, k4.w * vv); po = fmaf(q4.w, s[m*4+3], po);
        }
        // reduce over kg: 4 kgroups in-wave via xor-shuffle, then 4 waves via LDS
        po += __shfl_xor(po, 16, 64);
        po += __shfl_xor(po, 32, 64);
        if (lane < 16) wpart[wave][lane] = po;
        __syncthreads();
        if (tid < 16) {
            float o = wpart[0][tid] + wpart[1][tid] + wpart[2][tid] + wpart[3][tid];
            outp[((size_t)b * TB + t) * VD + v0 + tid] = f2bf(o);
        }
        __syncthreads();
    }
}

extern "C" void kernel_launch(void* const* d_in, const int* in_sizes, int n_in,
                              void* d_out, int out_size, void* d_ws, size_t ws_size,
                              hipStream_t stream) {
    const int*  ids = (const int*)d_in[0];
    const void* emb = d_in[1];
    const void* Wq  = d_in[2];
    const void* bq  = d_in[3];
    const void* Wk  = d_in[4];
    const void* bk  = d_in[5];
    const void* Wg  = d_in[6];
    const void* bg  = d_in[7];
    const void* Wv  = d_in[8];
    const void* bv  = d_in[9];
    const void* Wo  = d_in[10];
    const void* bo  = d_in[11];
    const void* Wh  = d_in[12];
    const void* bh  = d_in[13];
    (void)in_sizes; (void)n_in; (void)out_size; (void)ws_size;

    // ---- ws layout (~56 MB total) ----
    char* p = (char*)d_ws;
    auto alloc = [&](size_t bytes) { char* r = p; p += (bytes + 255) & ~(size_t)255; return (void*)r; };
    int*    flagp = (int*)alloc(4);
    ushort* biasc = (ushort*)alloc((size_t)39168 * 2);            // canonical bf16 biases
    ushort* bqc = biasc, *bkc = biasc + 1024, *bgc = biasc + 2048;
    ushort* bvc = biasc + 3072, *boc = biasc + 5120, *bhc = biasc + 7168;
    ushort* Wcat  = (ushort*)alloc((size_t)NL * 2560 * HH * 2);   // [q|k|g|v]^T per layer (2560,1024)
    ushort* Wot   = (ushort*)alloc((size_t)NL * OO * VD * 2);     // Wo^T (O,Vd)
    ushort* h     = (ushort*)alloc((size_t)NTOK * HH * 2);        // activations (reused in-place)
    ushort* Whalf = (ushort*)alloc((size_t)NHALF * OO * 2);       // W_head^T chunk (16000,O)

    // ---- transient buffers live inside d_out (dead before head GEMM writes it) ----
    float*  qkgv  = (float*)d_out;                                 // 40 MB
    ushort* scano = (ushort*)((char*)d_out + (size_t)NTOK * 2560 * 4);  // +8 MB <= 262 MB min d_out

    // ---- dtype probe + bias normalize ----
    probe_k<<<1, 256, 0, stream>>>((const ushort*)emb, flagp);
    cvt_bias_k<<<(NL*KK + 255) / 256, 256, 0, stream>>>(bq, bqc, NL*KK, flagp);
    cvt_bias_k<<<(NL*KK + 255) / 256, 256, 0, stream>>>(bk, bkc, NL*KK, flagp);
    cvt_bias_k<<<(NL*KK + 255) / 256, 256, 0, stream>>>(bg, bgc, NL*KK, flagp);
    cvt_bias_k<<<(NL*VD + 255) / 256, 256, 0, stream>>>(bv, bvc, NL*VD, flagp);
    cvt_bias_k<<<(NL*OO + 255) / 256, 256, 0, stream>>>(bo, boc, NL*OO, flagp);
    cvt_bias_k<<<(NVOC  + 255) / 256, 256, 0, stream>>>(bh, bhc, NVOC,  flagp);

    // ---- weight transposes (normalize to bf16) ----
    for (int l = 0; l < NL; l++) {
        ushort* Wc = Wcat + (size_t)l * 2560 * HH;
        transpose_k<<<dim3(KK/32, HH/32), 256, 0, stream>>>(Wq, (size_t)l*HH*KK, Wc,                   HH, KK, flagp);
        transpose_k<<<dim3(KK/32, HH/32), 256, 0, stream>>>(Wk, (size_t)l*HH*KK, Wc + (size_t)KK*HH,   HH, KK, flagp);
        transpose_k<<<dim3(KK/32, HH/32), 256, 0, stream>>>(Wg, (size_t)l*HH*KK, Wc + (size_t)2*KK*HH, HH, KK, flagp);
        transpose_k<<<dim3(VD/32, HH/32), 256, 0, stream>>>(Wv, (size_t)l*HH*VD, Wc + (size_t)3*KK*HH, HH, VD, flagp);
        transpose_k<<<dim3(OO/32, VD/32), 256, 0, stream>>>(Wo, (size_t)l*VD*OO, Wot + (size_t)l*OO*VD, VD, OO, flagp);
    }

    // ---- embedding ----
    gather_k<<<NTOK, 256, 0, stream>>>(ids, emb, h, flagp);

    // ---- layers ----
    for (int l = 0; l < NL; l++) {
        const ushort* Wc = Wcat + (size_t)l * 2560 * HH;
        gemm_bt<1><<<dim3(2560/128, NTOK/128), 256, 0, stream>>>(
            h, Wc, qkgv, bqc + l*KK, bkc + l*KK, bgc + l*KK, bvc + l*VD,
            HH, 2560, 0, flagp);
        scan_k<<<dim3(VD/16, BB), 256, 0, stream>>>(qkgv, scano);
        gemm_bt<0><<<dim3(OO/128, NTOK/128), 256, 0, stream>>>(
            scano, Wot + (size_t)l*OO*VD, h, boc + l*OO, nullptr, nullptr, nullptr,
            VD, OO, 0, flagp);
    }

    // ---- LM head: transpose W_head chunk -> GEMM, twice (ws budget) ----
    for (int c0 = 0; c0 < NVOC; c0 += NHALF) {
        transpose_k<<<dim3(NHALF/32, OO/32), 256, 0, stream>>>(Wh, (size_t)c0, Whalf, OO, NVOC, flagp);
        gemm_bt<2><<<dim3(NHALF/128, NTOK/128), 256, 0, stream>>>(
            h, Whalf, d_out, bhc + c0, nullptr, nullptr, nullptr,
            OO, NVOC, c0, flagp);
    }
}